// Round 2
// baseline (516.297 us; speedup 1.0000x reference)
//
#include <hip/hip_runtime.h>
#include <hip/hip_bf16.h>
#include <stdint.h>

#define SEQLEN 512
#define NBATCH 64
#define KDIM   512
#define HDIM   1024
#define MTOT   (SEQLEN * NBATCH)   // 32768
#define NTOT   (3 * HDIM)          // 3072
#define STRIDE (NBATCH * HDIM)     // 65536

typedef __attribute__((ext_vector_type(4))) float f32x4;
typedef _Float16 f16x8 __attribute__((ext_vector_type(8)));

// ---------- conversion: fp32 -> (hi, lo) fp16 split planes ---------------
// v = hi + lo exactly to ~2^-24 relative; 3-pass MFMA on splits ~= fp32 GEMM.
__global__ __launch_bounds__(256) void cvt_x(const float* __restrict__ x,
                                             _Float16* __restrict__ xh,
                                             _Float16* __restrict__ xl) {
    int i = blockIdx.x * 256 + threadIdx.x;   // M*K/8 threads, 8 elems each
    const float4* s = (const float4*)(x + (size_t)i * 8);
    float4 a = s[0], b = s[1];
    float v[8] = {a.x, a.y, a.z, a.w, b.x, b.y, b.z, b.w};
    f16x8 hi, lo;
#pragma unroll
    for (int j = 0; j < 8; ++j) {
        _Float16 h = (_Float16)v[j];
        hi[j] = h;
        lo[j] = (_Float16)(v[j] - (float)h);
    }
    *(f16x8*)(xh + (size_t)i * 8) = hi;
    *(f16x8*)(xl + (size_t)i * 8) = lo;
}

__global__ __launch_bounds__(256) void cvt_u(const float* __restrict__ Uc,
                                             const float* __restrict__ Ua,
                                             const float* __restrict__ Uh,
                                             _Float16* __restrict__ uh,
                                             _Float16* __restrict__ ul) {
    int i = blockIdx.x * 256 + threadIdx.x;   // NTOT*K/8 threads
    int n = i >> 6;
    int kb = (i & 63) * 8;
    const float* src = (n < HDIM) ? (Uc + (size_t)n * KDIM)
                     : (n < 2 * HDIM) ? (Ua + (size_t)(n - HDIM) * KDIM)
                     : (Uh + (size_t)(n - 2 * HDIM) * KDIM);
    const float4* s = (const float4*)(src + kb);
    float4 a = s[0], b = s[1];
    float v[8] = {a.x, a.y, a.z, a.w, b.x, b.y, b.z, b.w};
    f16x8 hi, lo;
#pragma unroll
    for (int j = 0; j < 8; ++j) {
        _Float16 h = (_Float16)v[j];
        hi[j] = h;
        lo[j] = (_Float16)(v[j] - (float)h);
    }
    *(f16x8*)(uh + (size_t)n * KDIM + kb) = hi;
    *(f16x8*)(ul + (size_t)n * KDIM + kb) = lo;
}

// --------- GEMM: proj[M][3072] = (Xh+Xl) · (Uh+Ul)^T, 3-pass split -------
// m97 structure: 128x128 tile, BK=32, 4 waves (2x2), 4x4 16x16x32 frags,
// global_load_lds width 16, single-buffered 2-barrier K-loop.
#define BM 128
#define BN 128
#define BK 32
#define NT_N (NTOT / BN)   // 24

__device__ __forceinline__ void gload16(const _Float16* g, _Float16* l) {
    __builtin_amdgcn_global_load_lds((const __attribute__((address_space(1))) void*)g,
                                     (__attribute__((address_space(3))) void*)l,
                                     16, 0, 0);
}

__global__ __launch_bounds__(256) void gemm_f16x2(const _Float16* __restrict__ Ah,
                                                  const _Float16* __restrict__ Al,
                                                  const _Float16* __restrict__ Bh,
                                                  const _Float16* __restrict__ Bl,
                                                  float* __restrict__ pc,
                                                  float* __restrict__ pa,
                                                  float* __restrict__ ph) {
    __shared__ _Float16 lds[4 * BM * BK];   // 32 KB: Ah | Al | Bh | Bl tiles
    _Float16* sAh = lds;
    _Float16* sAl = lds + BM * BK;
    _Float16* sBh = lds + 2 * BM * BK;
    _Float16* sBl = lds + 3 * BM * BK;

    int bid  = blockIdx.x;
    int bm   = bid / NT_N;          // A-panel-major
    int bn   = bid % NT_N;
    int tid  = threadIdx.x;
    int lane = tid & 63;
    int wave = tid >> 6;
    int wr   = wave >> 1;           // 2x2 wave grid, 64x64 each
    int wc   = wave & 1;

    // staging: thread t -> row t/4, k-chunk (t&3)*8; LDS byte off = t*16
    size_t row_off = (size_t)(tid >> 2) * KDIM + (tid & 3) * 8;
    const _Float16* gah0 = Ah + (size_t)bm * BM * KDIM + row_off;
    const _Float16* gal0 = Al + (size_t)bm * BM * KDIM + row_off;
    const _Float16* gbh0 = Bh + (size_t)bn * BN * KDIM + row_off;
    const _Float16* gbl0 = Bl + (size_t)bn * BN * KDIM + row_off;
    const size_t half_panel = (size_t)64 * KDIM;
    _Float16* lah = sAh + tid * 8;
    _Float16* lal = sAl + tid * 8;
    _Float16* lbh = sBh + tid * 8;
    _Float16* lbl = sBl + tid * 8;

    f32x4 acc[4][4];
#pragma unroll
    for (int mi = 0; mi < 4; ++mi)
#pragma unroll
        for (int ni = 0; ni < 4; ++ni)
            acc[mi][ni] = (f32x4){0.f, 0.f, 0.f, 0.f};

    int ro = lane & 15;           // row within 16x16 frag
    int ko = (lane >> 4) * 8;     // k offset within 32

    for (int kt = 0; kt < KDIM / BK; ++kt) {
        int g = kt * BK;
        gload16(gah0 + g, lah);
        gload16(gah0 + half_panel + g, lah + 2048);
        gload16(gal0 + g, lal);
        gload16(gal0 + half_panel + g, lal + 2048);
        gload16(gbh0 + g, lbh);
        gload16(gbh0 + half_panel + g, lbh + 2048);
        gload16(gbl0 + g, lbl);
        gload16(gbl0 + half_panel + g, lbl + 2048);
        __syncthreads();          // compiler drains vmcnt before barrier

        f16x8 ah[4], al[4], bh[4], bl[4];
#pragma unroll
        for (int mi = 0; mi < 4; ++mi) {
            int r = (wr * 64 + mi * 16 + ro) * BK + ko;
            ah[mi] = *(const f16x8*)(sAh + r);
            al[mi] = *(const f16x8*)(sAl + r);
        }
#pragma unroll
        for (int ni = 0; ni < 4; ++ni) {
            int r = (wc * 64 + ni * 16 + ro) * BK + ko;
            bh[ni] = *(const f16x8*)(sBh + r);
            bl[ni] = *(const f16x8*)(sBl + r);
        }
#pragma unroll
        for (int mi = 0; mi < 4; ++mi)
#pragma unroll
            for (int ni = 0; ni < 4; ++ni) {
                acc[mi][ni] = __builtin_amdgcn_mfma_f32_16x16x32_f16(
                    ah[mi], bl[ni], acc[mi][ni], 0, 0, 0);
                acc[mi][ni] = __builtin_amdgcn_mfma_f32_16x16x32_f16(
                    al[mi], bh[ni], acc[mi][ni], 0, 0, 0);
                acc[mi][ni] = __builtin_amdgcn_mfma_f32_16x16x32_f16(
                    ah[mi], bh[ni], acc[mi][ni], 0, 0, 0);
            }
        __syncthreads();
    }

    // epilogue: D col=lane&15 (N), row=(lane>>4)*4+r (M)  [m89-verified]
    int n0 = bn * BN;
    float* outp; int nb;
    if (n0 < HDIM)            { outp = pc; nb = n0; }
    else if (n0 < 2 * HDIM)   { outp = pa; nb = n0 - HDIM; }
    else                      { outp = ph; nb = n0 - 2 * HDIM; }

#pragma unroll
    for (int mi = 0; mi < 4; ++mi)
#pragma unroll
        for (int ni = 0; ni < 4; ++ni) {
            int m = bm * BM + wr * 64 + mi * 16 + (lane >> 4) * 4;
            int n = nb + wc * 64 + ni * 16 + (lane & 15);
#pragma unroll
            for (int r = 0; r < 4; ++r)
                outp[(size_t)(m + r) * HDIM + n] = acc[mi][ni][r];
        }
}

// ------------------------- recurrence ------------------------------------
// one thread per (b,j); 65536 threads; depth-8 register prefetch pipeline.
// ph lives in d_out (GEMM output), overwritten in-place with y (same thread
// owns both addresses; prefetch of out[s+8] precedes write of out[s+8]).
__global__ __launch_bounds__(256) void recur(const float* __restrict__ pc_a,
                                             const float* __restrict__ pa_a,
                                             float* out,
                                             const float* __restrict__ h0,
                                             const float* __restrict__ wc_,
                                             const float* __restrict__ bc_,
                                             const float* __restrict__ wa_,
                                             const float* __restrict__ ba_,
                                             const float* __restrict__ bh_) {
    int idx = blockIdx.x * 256 + threadIdx.x;   // 65536
    int j = idx & (HDIM - 1);
    float h  = h0[idx];
    float wc = wc_[j], bc = bc_[j];
    float wa = wa_[j], ba = ba_[j];
    float bh = bh_[j];

#define PF 8
    float pc[PF], pa[PF], ph[PF];
#pragma unroll
    for (int u = 0; u < PF; ++u) {
        pc[u] = pc_a[(size_t)u * STRIDE + idx];
        pa[u] = pa_a[(size_t)u * STRIDE + idx];
        ph[u] = out [(size_t)u * STRIDE + idx];
    }

    for (int sb = 0; sb < SEQLEN; sb += PF) {
#pragma unroll
        for (int u = 0; u < PF; ++u) {
            int s = sb + u;
            float vc = pc[u], va = pa[u], vh = ph[u];
            int sp = s + PF; sp = (sp < SEQLEN) ? sp : (SEQLEN - 1);  // clamped dead-prefetch
            pc[u] = pc_a[(size_t)sp * STRIDE + idx];
            pa[u] = pa_a[(size_t)sp * STRIDE + idx];
            ph[u] = out [(size_t)sp * STRIDE + idx];

            // match reference op order: proj = xU + b (GEMM is raw xU)
            float zc = (vc + bc) + wc * h;
            float za = (va + ba) + wa * h;
            float c  = 1.0f / (1.0f + expf(-zc));
            float a  = 1.0f + tanhf(za);
            float ht = tanhf((vh + bh) + a * h);
            h = c * h + (1.0f - c) * ht;
            out[(size_t)s * STRIDE + idx] = h;
        }
    }
    out[(size_t)SEQLEN * STRIDE + idx] = h;   // hn
}

// --------------------------- launch --------------------------------------
extern "C" void kernel_launch(void* const* d_in, const int* in_sizes, int n_in,
                              void* d_out, int out_size, void* d_ws, size_t ws_size,
                              hipStream_t stream) {
    const float* x_seq = (const float*)d_in[0];
    const float* h0    = (const float*)d_in[1];
    const float* U_c   = (const float*)d_in[2];
    const float* w_c   = (const float*)d_in[3];
    const float* b_c   = (const float*)d_in[4];
    const float* U_a   = (const float*)d_in[5];
    const float* w_a   = (const float*)d_in[6];
    const float* b_a   = (const float*)d_in[7];
    const float* U_h   = (const float*)d_in[8];
    const float* b_h   = (const float*)d_in[9];
    float* out = (float*)d_out;

    char* ws = (char*)d_ws;
    const size_t MB = 1024 * 1024;
    float*    ws_pc = (float*)ws;                        // 128 MB
    float*    ws_pa = (float*)(ws + 128 * MB);           // 128 MB
    _Float16* x_hi  = (_Float16*)(ws + 256 * MB);        // 32 MB
    _Float16* x_lo  = (_Float16*)(ws + 288 * MB);        // 32 MB
    _Float16* u_hi  = (_Float16*)(ws + 320 * MB);        // 3 MB
    _Float16* u_lo  = (_Float16*)(ws + 323 * MB);        // 3 MB  (total 326 MB)

    cvt_x<<<dim3(MTOT * KDIM / 8 / 256), dim3(256), 0, stream>>>(x_seq, x_hi, x_lo);
    cvt_u<<<dim3(NTOT * KDIM / 8 / 256), dim3(256), 0, stream>>>(U_c, U_a, U_h, u_hi, u_lo);
    gemm_f16x2<<<dim3((MTOT / BM) * NT_N), dim3(256), 0, stream>>>(
        x_hi, x_lo, u_hi, u_lo, ws_pc, ws_pa, out);
    recur<<<dim3(STRIDE / 256), dim3(256), 0, stream>>>(ws_pc, ws_pa, out, h0,
                                                        w_c, b_c, w_a, b_a, b_h);
}